// Round 7
// baseline (1944.256 us; speedup 1.0000x reference)
//
#include <hip/hip_runtime.h>

#define B_  32
#define T_  256
#define F_  64
#define C_  16
#define CO_ 16
#define P_  64
#define S_  32
#define K_  4
#define FC_ 1024   // F*C
#define OUTC 96
#define TT  8      // t-tile per block
#define NS  14     // TT + 6 halo slices (dilation*(K-1) = 6)
#define STR 40     // staging row stride in floats (bank-spread, 2-way max)

// v7: LDS-issue-count reduction (~543 -> ~145 wide LDS ops per wave).
// Ledger: monolithic dumps mandatory (v2); conv must be LDS-staged (v4);
// GEMM off critical path (v5); barriers immaterial (v3/v6). Remaining model:
// per-CU LDS pipe ~95us of issue time == kernel time. So: phase-1 reads x
// from GLOBAL (wave-uniform -> scalar-load path, off the LDS pipe); conv
// slice-hoisted (each x slice read once per c-half, not per (t,k)); point
// channels dumped straight from pv (no broadcast staging).
__global__ __launch_bounds__(512, 4) void tpc_fused(
    const float* __restrict__ x, const float* __restrict__ stat,
    const float* __restrict__ cw, const float* __restrict__ cb,
    const float* __restrict__ Wp, const float* __restrict__ bp,
    float* __restrict__ out)
{
    __shared__ __align__(16) float lds[18944];   // 74 KB
    float* xs   = lds;            // [0..14336) x slices (dead after conv)
    float* part = lds + 14336;    // [14336..18432) phase-1 partials
    float* pv   = lds + 18432;    // [18432..18944) relu'd point rows
    // dump staging: st[i] = lds + i*2560 (64 f x STR), aliases dead xs

    int tid = threadIdx.x;
    int blk = blockIdx.x;      // 0..1023
    int b  = blk >> 5;
    int t0 = (blk & 31) * TT;

    // ---- A) issue x staging loads into registers (held across phase 1) ----
    float4 stgv[7];
    #pragma unroll
    for (int it = 0; it < 7; ++it) {
        int v = it * 512 + tid;            // float4 id, NS*256 = 3584 total
        int slice = v >> 8;
        int pos   = v & 255;
        int tg = t0 - 6 + slice;
        stgv[it] = make_float4(0.f, 0.f, 0.f, 0.f);
        if (tg >= 0)
            stgv[it] = *(const float4*)(x + ((size_t)(b * T_ + tg)) * FC_ + pos * 4);
    }
    #pragma unroll
    for (int it = 0; it < 7; ++it)         // pin: keep loads issued here
        asm volatile("" : "+v"(stgv[it].x), "+v"(stgv[it].y),
                          "+v"(stgv[it].z), "+v"(stgv[it].w));

    // ---- B) phase 1: point GEMM from GLOBAL x (wave-uniform -> scalar path);
    //      exact v6 accumulation order, xs -> xrow0 only ----
    {
        int p  = tid & 63;
        int ks = __builtin_amdgcn_readfirstlane(tid >> 6);   // 0..7, provably uniform
        const float* xrow0 = x + ((size_t)(b * T_ + t0)) * FC_;
        float acc[TT];
        #pragma unroll
        for (int r = 0; r < TT; ++r) acc[r] = 0.f;
        int k0base = ks * 128;
        for (int kk = 0; kk < 128; kk += 4) {
            int k0 = k0base + kk;
            float w0 = Wp[(size_t)(k0 + 0) * P_ + p];
            float w1 = Wp[(size_t)(k0 + 1) * P_ + p];
            float w2 = Wp[(size_t)(k0 + 2) * P_ + p];
            float w3 = Wp[(size_t)(k0 + 3) * P_ + p];
            #pragma unroll
            for (int r = 0; r < TT; ++r) {
                float4 xv = *(const float4*)(xrow0 + r * FC_ + k0);
                acc[r] += xv.x * w0 + xv.y * w1 + xv.z * w2 + xv.w * w3;
            }
        }
        #pragma unroll
        for (int r = 0; r < TT; ++r)
            part[(ks * TT + r) * P_ + p] = acc[r];
    }

    // ---- C) staging ds_writes (latency was hidden under phase 1) ----
    #pragma unroll
    for (int it = 0; it < 7; ++it) {
        int v = it * 512 + tid;
        int slice = v >> 8;
        int pos   = v & 255;
        *(float4*)(xs + slice * FC_ + pos * 4) = stgv[it];
    }
    __syncthreads();   // covers: staging->conv, part->1b

    int p  = tid & 63;
    int co = tid & 15;
    int fh = tid >> 4;                     // 0..31 (local f within half)

    // ---- D) phase 1b: reduce + bias + static; relu -> pv ----
    {
        int r = tid >> 6;                  // row 0..7
        float s = bp[p];
        const float* wst = Wp + (size_t)FC_ * P_;
        #pragma unroll 8
        for (int si = 0; si < S_; ++si)
            s += stat[b * S_ + si] * wst[si * P_ + p];
        #pragma unroll
        for (int ks = 0; ks < 8; ++ks)
            s += part[(ks * TT + r) * P_ + p];
        pv[r * P_ + p] = fmaxf(s, 0.f);
    }

    // ---- E) conv (slice-hoisted, c-half split) + x passthrough -> regs ----
    float cv[2][TT], px[2][TT];
    #pragma unroll
    for (int half = 0; half < 2; ++half) {
        int f = half * 32 + fh;
        float bias = cb[f * CO_ + co];
        #pragma unroll
        for (int tl = 0; tl < TT; ++tl) cv[half][tl] = bias;
        #pragma unroll
        for (int ch = 0; ch < 2; ++ch) {
            // w[c'][k], c' = local c 0..7 (global c = ch*8+c'): 32 floats
            float w[32];
            const float4* wg = (const float4*)(cw + ((size_t)(f * CO_ + co)) * (C_ * K_)
                                               + ch * 32);
            #pragma unroll
            for (int j = 0; j < 8; ++j) {
                float4 t4 = wg[j];
                w[4 * j + 0] = t4.x; w[4 * j + 1] = t4.y;
                w[4 * j + 2] = t4.z; w[4 * j + 3] = t4.w;
            }
            // sweep slices once; each feeds all (tl,k) with tl+2k == s
            #pragma unroll
            for (int s = 0; s < NS; ++s) {
                const float* sp = xs + s * FC_ + f * C_ + ch * 8;
                float4 xa = *(const float4*)(sp);
                float4 xb = *(const float4*)(sp + 4);
                #pragma unroll
                for (int k = 0; k < K_; ++k) {
                    int tl = s - 2 * k;
                    if (tl >= 0 && tl < TT) {
                        cv[half][tl] += xa.x * w[0 * 4 + k] + xa.y * w[1 * 4 + k]
                                      + xa.z * w[2 * 4 + k] + xa.w * w[3 * 4 + k]
                                      + xb.x * w[4 * 4 + k] + xb.y * w[5 * 4 + k]
                                      + xb.z * w[6 * 4 + k] + xb.w * w[7 * 4 + k];
                    }
                }
            }
        }
        #pragma unroll
        for (int tl = 0; tl < TT; ++tl) {
            cv[half][tl] = fmaxf(cv[half][tl], 0.f);
            px[half][tl] = fmaxf(xs[(tl + 6) * FC_ + f * C_ + co], 0.f);
        }
    }
    __syncthreads();   // all xs reads drained (xs dead); pv visible

    // ---- F) dump loop: stage only ch 0..31; point read straight from pv ----
    int qf[3], qw4[3];
    #pragma unroll
    for (int j = 0; j < 3; ++j) {
        int q = j * 512 + tid;             // output float4 id within the row
        qf[j]  = q / 24;                   // f
        qw4[j] = q - qf[j] * 24;           // float4 slot within f's 96 ch
    }

    for (int tl = 0; tl < TT; ++tl) {
        float* st = lds + (tl & 1) * 2560; // aliases dead xs region
        st[fh * STR + co]             = px[0][tl];
        st[fh * STR + 16 + co]        = cv[0][tl];
        st[(fh + 32) * STR + co]      = px[1][tl];
        st[(fh + 32) * STR + 16 + co] = cv[1][tl];

        asm volatile("s_waitcnt lgkmcnt(0)" ::: "memory");
        __builtin_amdgcn_sched_barrier(0);
        __builtin_amdgcn_s_barrier();
        __builtin_amdgcn_sched_barrier(0);

        const float* pvt = pv + tl * P_;
        float4* dst = (float4*)(out + ((size_t)(b * T_ + t0 + tl)) * F_ * OUTC);
        #pragma unroll
        for (int j = 0; j < 3; ++j) {
            const float* srcp = (qw4[j] < 8)
                ? (st + qf[j] * STR + qw4[j] * 4)
                : (pvt + (qw4[j] - 8) * 4);
            float4 val = *(const float4*)srcp;
            dst[j * 512 + tid] = val;      // monolithic contiguous 24 KB row
        }
    }
}

extern "C" void kernel_launch(void* const* d_in, const int* in_sizes, int n_in,
                              void* d_out, int out_size, void* d_ws, size_t ws_size,
                              hipStream_t stream) {
    const float* x    = (const float*)d_in[0];
    const float* stat = (const float*)d_in[1];
    const float* cw   = (const float*)d_in[2];
    const float* cb   = (const float*)d_in[3];
    const float* Wp   = (const float*)d_in[4];
    const float* bp   = (const float*)d_in[5];
    float* out = (float*)d_out;

    tpc_fused<<<1024, 512, 0, stream>>>(x, stat, cw, cb, Wp, bp, out);
}

// Round 8
// 282.361 us; speedup vs baseline: 6.8857x; 6.8857x over previous
//
#include <hip/hip_runtime.h>

#define B_  32
#define T_  256
#define F_  64
#define C_  16
#define CO_ 16
#define P_  64
#define S_  32
#define K_  4
#define FC_ 1024   // F*C
#define OUTC 96
#define TT  8      // t-tile per block
#define NS  14     // TT + 6 halo slices (dilation*(K-1) = 6)

// v8 = v6 (best, 273.7us) with ONE change: phase-1 GEMM reads x from GLOBAL
// (wave-uniform broadcast, L1-hot after staging) instead of LDS -> removes
// 256 of ~512 ds_read_b128 per wave from the per-CU LDS pipe (~40us model).
// v7's spill disaster came from register pinning + conv restructure, NOT from
// this; v8 keeps v6's register profile exactly (no pinning, conv untouched).
// Ledger: monolithic dumps mandatory (v2); conv LDS-staged mandatory (v4);
// GEMM off critical path (v5); barriers immaterial (v3/v6).
__global__ __launch_bounds__(512, 4) void tpc_fused(
    const float* __restrict__ x, const float* __restrict__ stat,
    const float* __restrict__ cw, const float* __restrict__ cb,
    const float* __restrict__ Wp, const float* __restrict__ bp,
    float* __restrict__ out)
{
    __shared__ __align__(16) float lds[18944];   // 74 KB total
    float* xs   = lds;            // [0 .. 14336)  x slices (dead after conv)
    float* part = lds + 14336;    // [14336 .. 18432) phase-1 partials
    float* pv   = lds + 18432;    // [18432 .. 18944) relu'd point rows
    // staging: stg[i] = lds + i*6144, aliases xs after it is dead

    int tid = threadIdx.x;
    int blk = blockIdx.x;      // 0..1023
    int b  = blk >> 5;
    int t0 = (blk & 31) * TT;

    // ---- stage x[t0-6 .. t0+TT-1, :, :] into LDS (zero left pad) ----
    #pragma unroll
    for (int it = 0; it < 7; ++it) {
        int v = it * 512 + tid;            // float4 id, NS*256 = 3584 total
        int slice = v >> 8;
        int pos   = v & 255;
        int tg = t0 - 6 + slice;
        float4 val = make_float4(0.f, 0.f, 0.f, 0.f);
        if (tg >= 0)
            val = *(const float4*)(x + ((size_t)(b * T_ + tg)) * FC_ + pos * 4);
        *(float4*)(xs + slice * FC_ + pos * 4) = val;
    }
    __syncthreads();

    // ---- phase 1: point GEMM; x from GLOBAL (uniform broadcast, L1-hot) ----
    {
        int p  = tid & 63;
        int ks = __builtin_amdgcn_readfirstlane(tid >> 6);   // 0..7, uniform
        const float* xrow0 = x + ((size_t)(b * T_ + t0)) * FC_;
        float acc[TT];
        #pragma unroll
        for (int r = 0; r < TT; ++r) acc[r] = 0.f;
        int k0base = ks * 128;
        for (int kk = 0; kk < 128; kk += 4) {
            int k0 = k0base + kk;
            float w0 = Wp[(size_t)(k0 + 0) * P_ + p];
            float w1 = Wp[(size_t)(k0 + 1) * P_ + p];
            float w2 = Wp[(size_t)(k0 + 2) * P_ + p];
            float w3 = Wp[(size_t)(k0 + 3) * P_ + p];
            #pragma unroll
            for (int r = 0; r < TT; ++r) {
                float4 xv = *(const float4*)(xrow0 + r * FC_ + k0);
                acc[r] += xv.x * w0 + xv.y * w1 + xv.z * w2 + xv.w * w3;
            }
        }
        #pragma unroll
        for (int r = 0; r < TT; ++r)
            part[(ks * TT + r) * P_ + p] = acc[r];
    }
    __syncthreads();

    int p  = tid & 63;
    int co = tid & 15;
    int fh = tid >> 4;                     // 0..31 (local f within half)
    int fg = tid >> 6;                     // 0..7

    // ---- phase 1b: reduce + bias + static; relu -> pv (disjoint region) ----
    {
        int r = tid >> 6;                  // row 0..7
        float s = bp[p];
        const float* wst = Wp + (size_t)FC_ * P_;
        #pragma unroll 8
        for (int si = 0; si < S_; ++si)
            s += stat[b * S_ + si] * wst[si * P_ + p];
        #pragma unroll
        for (int ks = 0; ks < 8; ++ks)
            s += part[(ks * TT + r) * P_ + p];
        pv[r * P_ + p] = fmaxf(s, 0.f);
    }

    // ---- conv + x passthrough -> registers (xs reads, no barriers) ----
    float cv[2][TT], px[2][TT];
    #pragma unroll
    for (int half = 0; half < 2; ++half) {
        int f = half * 32 + fh;
        float w[64];
        const float4* wg = (const float4*)(cw + ((size_t)(f * CO_ + co)) * (C_ * K_));
        #pragma unroll
        for (int j = 0; j < 16; ++j) {
            float4 t4 = wg[j];
            w[4 * j + 0] = t4.x; w[4 * j + 1] = t4.y;
            w[4 * j + 2] = t4.z; w[4 * j + 3] = t4.w;
        }
        float bias = cb[f * CO_ + co];
        #pragma unroll
        for (int tl = 0; tl < TT; ++tl) {
            float temp = bias;
            #pragma unroll
            for (int k = 0; k < K_; ++k) {
                const float* sp = xs + (tl + 2 * k) * FC_ + f * C_;
                #pragma unroll
                for (int c4 = 0; c4 < 4; ++c4) {
                    float4 xv = *(const float4*)(sp + c4 * 4);
                    temp += xv.x * w[(c4 * 4 + 0) * 4 + k];
                    temp += xv.y * w[(c4 * 4 + 1) * 4 + k];
                    temp += xv.z * w[(c4 * 4 + 2) * 4 + k];
                    temp += xv.w * w[(c4 * 4 + 3) * 4 + k];
                }
            }
            cv[half][tl] = fmaxf(temp, 0.f);
            px[half][tl] = fmaxf(xs[(tl + 6) * FC_ + f * C_ + co], 0.f);
        }
    }
    __syncthreads();   // all xs reads drained (xs now dead); pv visible

    // hoist pv rows for this thread's p
    float pvr[TT];
    #pragma unroll
    for (int tl = 0; tl < TT; ++tl)
        pvr[tl] = pv[tl * P_ + p];

    // ---- pure dump loop: 8 iterations, 24 KB monolithic stores ----
    for (int tl = 0; tl < TT; ++tl) {
        float* st = lds + (tl & 1) * 6144;   // aliases dead xs region
        // stage full t-row [f=0..63][96] from registers
        st[fh * OUTC + co]               = px[0][tl];
        st[fh * OUTC + 16 + co]          = cv[0][tl];
        st[(fh + 32) * OUTC + co]        = px[1][tl];
        st[(fh + 32) * OUTC + 16 + co]   = cv[1][tl];
        float pvv = pvr[tl];
        #pragma unroll
        for (int fo = 0; fo < 8; ++fo)
            st[(fo * 8 + fg) * OUTC + 32 + p] = pvv;

        // single lgkm-only barrier (double buffer; prev readers of this buffer
        // drained their reads at the previous barrier; stores never drained)
        asm volatile("s_waitcnt lgkmcnt(0)" ::: "memory");
        __builtin_amdgcn_sched_barrier(0);
        __builtin_amdgcn_s_barrier();
        __builtin_amdgcn_sched_barrier(0);

        // dump 24 KB contiguous (one full t row, full 128B lines)
        const float4* src = (const float4*)st;
        float4* dst = (float4*)(out + ((size_t)(b * T_ + t0 + tl)) * F_ * OUTC);
        dst[tid]        = src[tid];
        dst[512 + tid]  = src[512 + tid];
        dst[1024 + tid] = src[1024 + tid];
    }
}

extern "C" void kernel_launch(void* const* d_in, const int* in_sizes, int n_in,
                              void* d_out, int out_size, void* d_ws, size_t ws_size,
                              hipStream_t stream) {
    const float* x    = (const float*)d_in[0];
    const float* stat = (const float*)d_in[1];
    const float* cw   = (const float*)d_in[2];
    const float* cb   = (const float*)d_in[3];
    const float* Wp   = (const float*)d_in[4];
    const float* bp   = (const float*)d_in[5];
    float* out = (float*)d_out;

    tpc_fused<<<1024, 512, 0, stream>>>(x, stat, cw, cb, Wp, bp, out);
}